// Round 3
// baseline (481.960 us; speedup 1.0000x reference)
//
#include <hip/hip_runtime.h>

#define DIM 1024
#define NQ 6

// Two-kernel split (R3): the fused kernel's __syncthreads forces a
// vmcnt(0) drain every row, coupling the read stream, write stream and
// reduction into one serialized critical path (R0/R1 falsified DS-throughput
// and barrier-count theories; kernel stuck at ~110us vs 85us stream floor).
//
// Pass 1: block-per-row, NO LDS / NO barrier. Each wave reduces its 8
//   partials to full-wave totals via DPP butterfly + 2 DS shuffles; lanes
//   0..7 store 8 floats -> qpart[row][wave][8] (8 MiB, stays in L2/L3).
//   Pure read stream, low VGPR, 8 waves/SIMD.
// Pass 2: block-per-row, reads qpart row (32 floats, broadcast, L3-hot),
//   cos + outer product + relu, streams 256 MiB out. Write stream
//   saturates even at low occupancy (harness fills: 6.4 TB/s @ 10% occ).
//
// Butterfly (verified, unchanged since R0):
//   xor1 -> quad_perm[1,0,3,2] (0xB1)
//   xor2 -> quad_perm[2,3,0,1] (0x4E)
//   xor7 -> row_half_mirror    (0x141)
//   xor8 -> row_ror:8          (0x128)
// fold bits s1=(l^(l>>2))&1, s2=(l^(l>>1))&1, s3=(l>>2)&1, vperm=4s1+2s2+s3.

__device__ __forceinline__ float4 add4(float4 a, float4 b) {
    return make_float4(a.x + b.x, a.y + b.y, a.z + b.z, a.w + b.w);
}

template <int CTRL>
__device__ __forceinline__ float dpp_mov(float x) {
    return __int_as_float(__builtin_amdgcn_update_dpp(
        0, __float_as_int(x), CTRL, 0xF, 0xF, true));
}

__device__ __forceinline__ float butterfly6(const float* p, int s1, int s2, int s3) {
    float r4[4];
#pragma unroll
    for (int i = 0; i < 4; ++i) {
        float send = s1 ? p[i] : p[i + 4];
        float keep = s1 ? p[i + 4] : p[i];
        r4[i] = keep + dpp_mov<0xB1>(send);
    }
    float r2[2];
#pragma unroll
    for (int i = 0; i < 2; ++i) {
        float send = s2 ? r4[i] : r4[i + 2];
        float keep = s2 ? r4[i + 2] : r4[i];
        r2[i] = keep + dpp_mov<0x4E>(send);
    }
    float send = s3 ? r2[0] : r2[1];
    float keep = s3 ? r2[1] : r2[0];
    float r1 = keep + dpp_mov<0x141>(send);
    r1 += dpp_mov<0x128>(r1);       // xor8 via row_ror:8 (vperm invariant mod 16)
    r1 += __shfl_xor(r1, 16, 64);   // DS swizzle
    r1 += __shfl_xor(r1, 32, 64);   // DS permute
    return r1;
}

// ---------------- Pass 1: x -> per-wave partial sums ----------------
__global__ __launch_bounds__(256, 8) void ffq_pass1(
    const float* __restrict__ x,
    const float* __restrict__ w1,
    float* __restrict__ qpart,      // [n_rows][4 waves][8]
    int n_rows)
{
    const int t    = threadIdx.x;
    const int lane = t & 63;
    const int wave = t >> 6;
    const int d0   = t * 4;

    float w1f[NQ][4];
#pragma unroll
    for (int q = 0; q < NQ; ++q) {
        float4 v = *reinterpret_cast<const float4*>(w1 + q * DIM + d0);
        w1f[q][0] = v.x; w1f[q][1] = v.y; w1f[q][2] = v.z; w1f[q][3] = v.w;
    }

    const int s1 = (lane ^ (lane >> 2)) & 1;
    const int s2 = (lane ^ (lane >> 1)) & 1;
    const int s3 = (lane >> 2) & 1;
    const int vperm = 4 * s1 + 2 * s2 + s3;

    const int stride = gridDim.x;
    int r = blockIdx.x;

    float4 xv = make_float4(0.f, 0.f, 0.f, 0.f);
    if (r < n_rows) xv = *reinterpret_cast<const float4*>(x + (size_t)r * DIM + d0);

    while (r < n_rows) {
        const int rn = r + stride;
        float4 xn = make_float4(0.f, 0.f, 0.f, 0.f);
        if (rn < n_rows) xn = *reinterpret_cast<const float4*>(x + (size_t)rn * DIM + d0);

        float p[8];
#pragma unroll
        for (int q = 0; q < NQ; ++q)
            p[q] = fmaf(xv.x, w1f[q][0],
                   fmaf(xv.y, w1f[q][1],
                   fmaf(xv.z, w1f[q][2], xv.w * w1f[q][3])));
        p[6] = 0.f; p[7] = 0.f;

        float r1 = butterfly6(p, s1, s2, s3);

        if (lane < 8)
            qpart[(size_t)r * 32 + wave * 8 + vperm] = r1;  // 32B/wave, contiguous

        xv = xn;
        r = rn;
    }
}

// ---------------- Pass 2: partials -> cos -> out ----------------
__global__ __launch_bounds__(256, 4) void ffq_pass2(
    const float* __restrict__ qpart,
    const float* __restrict__ b1,
    const float* __restrict__ theta,
    const float* __restrict__ w2,
    const float* __restrict__ b2,
    float* __restrict__ out,
    int n_rows)
{
    const int t  = threadIdx.x;
    const int d0 = t * 4;

    float w2f[4][NQ];
    {
        const float4* wp = reinterpret_cast<const float4*>(w2 + (size_t)d0 * NQ);
        float* flat = &w2f[0][0];
#pragma unroll
        for (int i = 0; i < 6; ++i) {
            float4 v = wp[i];
            flat[4 * i + 0] = v.x; flat[4 * i + 1] = v.y;
            flat[4 * i + 2] = v.z; flat[4 * i + 3] = v.w;
        }
    }
    const float4 b2v = *reinterpret_cast<const float4*>(b2 + d0);
    float b1f[NQ], ctf[NQ];
#pragma unroll
    for (int q = 0; q < NQ; ++q) {
        b1f[q] = b1[q];
        ctf[q] = __cosf(theta[q]);
    }

    const int stride = gridDim.x;
    for (int r = blockIdx.x; r < n_rows; r += stride) {
        const float4* rp = reinterpret_cast<const float4*>(qpart + (size_t)r * 32);
        // sum the 4 wave partials (broadcast loads, L2/L3-hot)
        float4 alo = add4(add4(rp[0], rp[2]), add4(rp[4], rp[6]));  // q0..q3
        float4 ahi = add4(add4(rp[1], rp[3]), add4(rp[5], rp[7]));  // q4..q5

        float qv[NQ];
        qv[0] = alo.x; qv[1] = alo.y; qv[2] = alo.z; qv[3] = alo.w;
        qv[4] = ahi.x; qv[5] = ahi.y;
#pragma unroll
        for (int q = 0; q < NQ; ++q)
            qv[q] = __cosf(qv[q] + b1f[q]) * ctf[q];

        float4 o = b2v;
#pragma unroll
        for (int q = 0; q < NQ; ++q) {
            o.x = fmaf(qv[q], w2f[0][q], o.x);
            o.y = fmaf(qv[q], w2f[1][q], o.y);
            o.z = fmaf(qv[q], w2f[2][q], o.z);
            o.w = fmaf(qv[q], w2f[3][q], o.w);
        }
        o.x = fmaxf(o.x, 0.f); o.y = fmaxf(o.y, 0.f);
        o.z = fmaxf(o.z, 0.f); o.w = fmaxf(o.w, 0.f);
        *reinterpret_cast<float4*>(out + (size_t)r * DIM + d0) = o;
    }
}

// ---------------- Fallback: fused single kernel (R1 version) ----------------
__global__ __launch_bounds__(256, 4) void ffq_fused(
    const float* __restrict__ x,
    const float* __restrict__ w1,
    const float* __restrict__ b1,
    const float* __restrict__ theta,
    const float* __restrict__ w2,
    const float* __restrict__ b2,
    float* __restrict__ out,
    int n_rows)
{
    const int t    = threadIdx.x;
    const int lane = t & 63;
    const int wave = t >> 6;
    const int d0   = t * 4;

    float w1f[NQ][4];
#pragma unroll
    for (int q = 0; q < NQ; ++q) {
        float4 v = *reinterpret_cast<const float4*>(w1 + q * DIM + d0);
        w1f[q][0] = v.x; w1f[q][1] = v.y; w1f[q][2] = v.z; w1f[q][3] = v.w;
    }
    float w2f[4][NQ];
    {
        const float4* wp = reinterpret_cast<const float4*>(w2 + (size_t)d0 * NQ);
        float* flat = &w2f[0][0];
#pragma unroll
        for (int i = 0; i < 6; ++i) {
            float4 v = wp[i];
            flat[4 * i + 0] = v.x; flat[4 * i + 1] = v.y;
            flat[4 * i + 2] = v.z; flat[4 * i + 3] = v.w;
        }
    }
    const float4 b2v = *reinterpret_cast<const float4*>(b2 + d0);
    float b1f[NQ], ctf[NQ];
#pragma unroll
    for (int q = 0; q < NQ; ++q) {
        b1f[q] = b1[q];
        ctf[q] = __cosf(theta[q]);
    }

    const int s1 = (lane ^ (lane >> 2)) & 1;
    const int s2 = (lane ^ (lane >> 1)) & 1;
    const int s3 = (lane >> 2) & 1;
    const int vperm = 4 * s1 + 2 * s2 + s3;

    __shared__ __align__(16) float red[2][4][8];

    const int stride = gridDim.x;
    int r = blockIdx.x;
    int par = 0;

    float4 xv = make_float4(0.f, 0.f, 0.f, 0.f);
    if (r < n_rows) xv = *reinterpret_cast<const float4*>(x + (size_t)r * DIM + d0);

    while (r < n_rows) {
        const int rn = r + stride;
        float4 xn = make_float4(0.f, 0.f, 0.f, 0.f);
        if (rn < n_rows) xn = *reinterpret_cast<const float4*>(x + (size_t)rn * DIM + d0);

        float p[8];
#pragma unroll
        for (int q = 0; q < NQ; ++q)
            p[q] = fmaf(xv.x, w1f[q][0],
                   fmaf(xv.y, w1f[q][1],
                   fmaf(xv.z, w1f[q][2], xv.w * w1f[q][3])));
        p[6] = 0.f; p[7] = 0.f;

        float r1 = butterfly6(p, s1, s2, s3);

        if (lane < 8) red[par][wave][vperm] = r1;
        __syncthreads();

        const float4* rp = reinterpret_cast<const float4*>(&red[par][0][0]);
        float4 slo = add4(add4(rp[0], rp[2]), add4(rp[4], rp[6]));
        float4 shi = add4(add4(rp[1], rp[3]), add4(rp[5], rp[7]));
        float qv[NQ];
        qv[0] = slo.x; qv[1] = slo.y; qv[2] = slo.z; qv[3] = slo.w;
        qv[4] = shi.x; qv[5] = shi.y;
#pragma unroll
        for (int q = 0; q < NQ; ++q)
            qv[q] = __cosf(qv[q] + b1f[q]) * ctf[q];

        float4 o = b2v;
#pragma unroll
        for (int q = 0; q < NQ; ++q) {
            o.x = fmaf(qv[q], w2f[0][q], o.x);
            o.y = fmaf(qv[q], w2f[1][q], o.y);
            o.z = fmaf(qv[q], w2f[2][q], o.z);
            o.w = fmaf(qv[q], w2f[3][q], o.w);
        }
        o.x = fmaxf(o.x, 0.f); o.y = fmaxf(o.y, 0.f);
        o.z = fmaxf(o.z, 0.f); o.w = fmaxf(o.w, 0.f);
        *reinterpret_cast<float4*>(out + (size_t)r * DIM + d0) = o;

        xv = xn;
        r = rn;
        par ^= 1;
    }
}

extern "C" void kernel_launch(void* const* d_in, const int* in_sizes, int n_in,
                              void* d_out, int out_size, void* d_ws, size_t ws_size,
                              hipStream_t stream) {
    const float* x     = (const float*)d_in[0];
    const float* w1    = (const float*)d_in[1];
    const float* b1    = (const float*)d_in[2];
    const float* theta = (const float*)d_in[3];
    const float* w2    = (const float*)d_in[4];
    const float* b2    = (const float*)d_in[5];
    float* out = (float*)d_out;

    const int n_rows = in_sizes[0] / DIM;  // B*S = 65536
    const size_t need = (size_t)n_rows * 32 * sizeof(float);  // 8.4 MB

    if (d_ws != nullptr && ws_size >= need) {
        float* qpart = (float*)d_ws;
        ffq_pass1<<<2048, 256, 0, stream>>>(x, w1, qpart, n_rows);
        ffq_pass2<<<2048, 256, 0, stream>>>(qpart, b1, theta, w2, b2, out, n_rows);
    } else {
        ffq_fused<<<1024, 256, 0, stream>>>(x, w1, b1, theta, w2, b2, out, n_rows);
    }
}

// Round 4
// 462.138 us; speedup vs baseline: 1.0429x; 1.0429x over previous
//
#include <hip/hip_runtime.h>

#define DIM 1024
#define NQ 6

// Wave-autonomous rows (R4). Root cause theory: the fused kernel's per-row
// __syncthreads forces s_waitcnt vmcnt(0) (compiler-mandated before
// s_barrier), draining the prefetch loads AND the posted-store stream every
// row for every wave -> correlated pipeline flush, 4.6 TB/s vs 6.3 ceiling.
// R0 (DS throughput) and R1 (barrier count / ILP) were null because neither
// removed the drain; R3's split removed it but added launch + L3-latency
// serial chains.
//
// Here: one WAVE owns a whole row (16 floats/lane). No __syncthreads in the
// main loop at all:
//  - w1 fragment in registers (24 float4 / lane).
//  - wave reduction: DPP butterfly (xor1/2/7/8) + ds_swizzle (xor16/32).
//  - qv broadcast via wave-PRIVATE LDS slot red[wave] (same-wave ds_write ->
//    ds_read is ordered by lgkmcnt; no barrier needed).
//  - w2 staged once into LDS in per-lane layout, XOR-swizzled
//    (byte ^= (l&7)<<4) so the 24 ds_read_b128/row are conflict-free
//    (consecutive-8 lanes hit 8 distinct 16B bank groups). Single barrier
//    at startup only.
//  - next-row prefetch (4 float4/lane) stays in flight across iterations;
//    stores retire asynchronously (no drain points).
// Butterfly fold bits s1=(l^(l>>2))&1, s2=(l^(l>>1))&1, s3=(l>>2)&1,
// vperm=4s1+2s2+s3; vperm->lane map within each 8-group is bijective.

__device__ __forceinline__ float4 add4(float4 a, float4 b) {
    return make_float4(a.x + b.x, a.y + b.y, a.z + b.z, a.w + b.w);
}

template <int CTRL>
__device__ __forceinline__ float dpp_mov(float x) {
    return __int_as_float(__builtin_amdgcn_update_dpp(
        0, __float_as_int(x), CTRL, 0xF, 0xF, true));
}

__device__ __forceinline__ float butterfly6(const float* p, int s1, int s2, int s3) {
    float r4[4];
#pragma unroll
    for (int i = 0; i < 4; ++i) {
        float send = s1 ? p[i] : p[i + 4];
        float keep = s1 ? p[i + 4] : p[i];
        r4[i] = keep + dpp_mov<0xB1>(send);   // xor1
    }
    float r2[2];
#pragma unroll
    for (int i = 0; i < 2; ++i) {
        float send = s2 ? r4[i] : r4[i + 2];
        float keep = s2 ? r4[i + 2] : r4[i];
        r2[i] = keep + dpp_mov<0x4E>(send);   // xor2
    }
    float send = s3 ? r2[0] : r2[1];
    float keep = s3 ? r2[1] : r2[0];
    float r1 = keep + dpp_mov<0x141>(send);   // xor7 (row_half_mirror)
    r1 += dpp_mov<0x128>(r1);                 // xor8 via row_ror:8
    r1 += __shfl_xor(r1, 16, 64);             // DS swizzle
    r1 += __shfl_xor(r1, 32, 64);             // DS permute
    return r1;
}

// swizzled float index of w2 fragment (lane l, out-chunk j, qubit q)
__device__ __forceinline__ int w2off(int l, int j, int q) {
    return (((l * 384) + (j * 6 + q) * 16) ^ ((l & 7) << 4)) >> 2;
}

__global__ __launch_bounds__(256, 2) void ffq_waverow(
    const float* __restrict__ x,
    const float* __restrict__ w1,
    const float* __restrict__ b1,
    const float* __restrict__ theta,
    const float* __restrict__ w2,
    const float* __restrict__ b2,
    float* __restrict__ out,
    int n_rows)
{
    const int t    = threadIdx.x;
    const int lane = t & 63;
    const int wave = t >> 6;

    __shared__ float w2L[64 * 96];                 // 24.6 KiB, swizzled per-lane
    __shared__ __align__(16) float red[4][8];      // wave-private qv slots

    // ---- one-time staging of w2 into swizzled LDS layout ----
    for (int idx = t; idx < 64 * 96; idx += 256) {
        const int c = idx & 3;
        const int q = (idx >> 2) % 6;
        const int j = (idx / 24) & 3;
        const int l = idx / 96;
        // w2 is [DIM][NQ] row-major; dim d = j*256 + l*4 + c
        w2L[w2off(l, j, q) + c] = w2[(size_t)(j * 256 + l * 4 + c) * NQ + q];
    }

    // ---- per-lane register caches ----
    float4 w1f[NQ][4];   // w1f[q][j] = w1[q][j*256 + lane*4 .. +4)
#pragma unroll
    for (int q = 0; q < NQ; ++q)
#pragma unroll
        for (int j = 0; j < 4; ++j)
            w1f[q][j] = *reinterpret_cast<const float4*>(w1 + q * DIM + j * 256 + lane * 4);

    float4 b2v[4];
#pragma unroll
    for (int j = 0; j < 4; ++j)
        b2v[j] = *reinterpret_cast<const float4*>(b2 + j * 256 + lane * 4);

    float b1f[NQ], ctf[NQ];
#pragma unroll
    for (int q = 0; q < NQ; ++q) {
        b1f[q] = b1[q];
        ctf[q] = __cosf(theta[q]);
    }

    const int s1 = (lane ^ (lane >> 2)) & 1;
    const int s2 = (lane ^ (lane >> 1)) & 1;
    const int s3 = (lane >> 2) & 1;
    const int vperm = 4 * s1 + 2 * s2 + s3;

    __syncthreads();   // the ONLY barrier: w2L ready

    const int gw      = blockIdx.x * 4 + wave;   // global wave id
    const int wstride = gridDim.x * 4;
    const float* w2Ll = w2L;                      // base; offsets are absolute

    int r = gw;
    float4 xc[4];
#pragma unroll
    for (int j = 0; j < 4; ++j) xc[j] = make_float4(0.f, 0.f, 0.f, 0.f);
    if (r < n_rows) {
#pragma unroll
        for (int j = 0; j < 4; ++j)
            xc[j] = *reinterpret_cast<const float4*>(x + (size_t)r * DIM + j * 256 + lane * 4);
    }

    while (r < n_rows) {
        // prefetch next row (stays in flight across the whole iteration;
        // nothing below drains vmcnt)
        const int rn = r + wstride;
        float4 xn[4];
#pragma unroll
        for (int j = 0; j < 4; ++j) xn[j] = make_float4(0.f, 0.f, 0.f, 0.f);
        if (rn < n_rows) {
#pragma unroll
            for (int j = 0; j < 4; ++j)
                xn[j] = *reinterpret_cast<const float4*>(x + (size_t)rn * DIM + j * 256 + lane * 4);
        }

        // per-lane partials over 16 elements for each qubit
        float p[8];
#pragma unroll
        for (int q = 0; q < NQ; ++q) {
            float a = 0.f;
#pragma unroll
            for (int j = 0; j < 4; ++j) {
                a = fmaf(xc[j].x, w1f[q][j].x,
                    fmaf(xc[j].y, w1f[q][j].y,
                    fmaf(xc[j].z, w1f[q][j].z,
                    fmaf(xc[j].w, w1f[q][j].w, a))));
            }
            p[q] = a;
        }
        p[6] = 0.f; p[7] = 0.f;

        // wave-wide reduction -> every lane holds total for its vperm
        float r1 = butterfly6(p, s1, s2, s3);

        // wave-private LDS broadcast (no barrier: same-wave lgkmcnt ordering)
        if (lane < 8) red[wave][vperm] = r1;
        const float4 qlo = *reinterpret_cast<const float4*>(&red[wave][0]);
        const float4 qhi = *reinterpret_cast<const float4*>(&red[wave][4]);

        float qv[NQ];
        qv[0] = qlo.x; qv[1] = qlo.y; qv[2] = qlo.z; qv[3] = qlo.w;
        qv[4] = qhi.x; qv[5] = qhi.y;
#pragma unroll
        for (int q = 0; q < NQ; ++q)
            qv[q] = __cosf(qv[q] + b1f[q]) * ctf[q];

        // outer product: 16 outputs/lane, w2 from swizzled LDS (conflict-free b128)
#pragma unroll
        for (int j = 0; j < 4; ++j) {
            float4 o = b2v[j];
#pragma unroll
            for (int q = 0; q < NQ; ++q) {
                const float4 w = *reinterpret_cast<const float4*>(w2Ll + w2off(lane, j, q));
                o.x = fmaf(qv[q], w.x, o.x);
                o.y = fmaf(qv[q], w.y, o.y);
                o.z = fmaf(qv[q], w.z, o.z);
                o.w = fmaf(qv[q], w.w, o.w);
            }
            o.x = fmaxf(o.x, 0.f); o.y = fmaxf(o.y, 0.f);
            o.z = fmaxf(o.z, 0.f); o.w = fmaxf(o.w, 0.f);
            *reinterpret_cast<float4*>(out + (size_t)r * DIM + j * 256 + lane * 4) = o;
        }

#pragma unroll
        for (int j = 0; j < 4; ++j) xc[j] = xn[j];
        r = rn;
    }
}

extern "C" void kernel_launch(void* const* d_in, const int* in_sizes, int n_in,
                              void* d_out, int out_size, void* d_ws, size_t ws_size,
                              hipStream_t stream) {
    const float* x     = (const float*)d_in[0];
    const float* w1    = (const float*)d_in[1];
    const float* b1    = (const float*)d_in[2];
    const float* theta = (const float*)d_in[3];
    const float* w2    = (const float*)d_in[4];
    const float* b2    = (const float*)d_in[5];
    float* out = (float*)d_out;

    const int n_rows = in_sizes[0] / DIM;  // B*S = 65536
    // 512 blocks = exactly 2 blocks/CU residency at ~200 VGPR (2 waves/SIMD):
    // 2048 waves, 32 rows each, all blocks start and finish together.
    ffq_waverow<<<512, 256, 0, stream>>>(x, w1, b1, theta, w2, b2, out, n_rows);
}

// Round 5
// 441.779 us; speedup vs baseline: 1.0910x; 1.0461x over previous
//
#include <hip/hip_runtime.h>

#define DIM 1024
#define NQ 6

// R5: R0-DPP fused structure (best known, 440.0us) + NON-TEMPORAL streams.
// Theory: the timed region's two 1-GiB fills leave L3 full of dirty lines;
// default allocating loads/stores of our 512 MiB stream evict them ->
// foreign write-back traffic on top of our own (~650-768 MiB effective,
// matching the observed ~110us vs the 85us/512MiB floor). This is invisible
// to compute restructuring - consistent with R0/R1/R3/R4 all being null or
// negative. nt loads/stores skip cache allocation, so our kernel moves only
// its own bytes.
//
// Butterfly (verified R0): xor1->quad_perm 0xB1, xor2->0x4E,
// xor7->row_half_mirror 0x141, xor8->row_ror:8 0x128; fold bits
// s1=(l^(l>>2))&1, s2=(l^(l>>1))&1, s3=(l>>2)&1, vperm=4s1+2s2+s3.

typedef float v4f __attribute__((ext_vector_type(4)));

__device__ __forceinline__ v4f add4(v4f a, v4f b) { return a + b; }

template <int CTRL>
__device__ __forceinline__ float dpp_mov(float x) {
    return __int_as_float(__builtin_amdgcn_update_dpp(
        0, __float_as_int(x), CTRL, 0xF, 0xF, true));
}

__global__ __launch_bounds__(256, 4) void ffq_fused(
    const float* __restrict__ x,
    const float* __restrict__ w1,
    const float* __restrict__ b1,
    const float* __restrict__ theta,
    const float* __restrict__ w2,
    const float* __restrict__ b2,
    float* __restrict__ out,
    int n_rows)
{
    const int t    = threadIdx.x;
    const int lane = t & 63;
    const int wave = t >> 6;
    const int d0   = t * 4;

    // ---- register-cached weights (reused across all rows; normal loads) ----
    float w1f[NQ][4];
#pragma unroll
    for (int q = 0; q < NQ; ++q) {
        v4f v = *reinterpret_cast<const v4f*>(w1 + q * DIM + d0);
        w1f[q][0] = v.x; w1f[q][1] = v.y; w1f[q][2] = v.z; w1f[q][3] = v.w;
    }
    float w2f[4][NQ];  // w2f[i][q] = w2[(d0+i)*6 + q]
    {
        const v4f* wp = reinterpret_cast<const v4f*>(w2 + (size_t)d0 * NQ);
        float* flat = &w2f[0][0];
#pragma unroll
        for (int i = 0; i < 6; ++i) {
            v4f v = wp[i];
            flat[4 * i + 0] = v.x; flat[4 * i + 1] = v.y;
            flat[4 * i + 2] = v.z; flat[4 * i + 3] = v.w;
        }
    }
    const v4f b2v = *reinterpret_cast<const v4f*>(b2 + d0);
    float b1f[NQ], ctf[NQ];
#pragma unroll
    for (int q = 0; q < NQ; ++q) {
        b1f[q] = b1[q];
        ctf[q] = __cosf(theta[q]);
    }

    const int s1 = (lane ^ (lane >> 2)) & 1;
    const int s2 = (lane ^ (lane >> 1)) & 1;
    const int s3 = (lane >> 2) & 1;
    const int vperm = 4 * s1 + 2 * s2 + s3;

    __shared__ __align__(16) float red[2][4][8];  // [parity][wave][value]

    const int stride = gridDim.x;
    int r = blockIdx.x;
    int par = 0;

    v4f xv = (v4f){0.f, 0.f, 0.f, 0.f};
    if (r < n_rows)
        xv = __builtin_nontemporal_load(
            reinterpret_cast<const v4f*>(x + (size_t)r * DIM + d0));

    while (r < n_rows) {
        // prefetch next row (non-temporal: no L2/L3 allocation)
        const int rn = r + stride;
        v4f xn = (v4f){0.f, 0.f, 0.f, 0.f};
        if (rn < n_rows)
            xn = __builtin_nontemporal_load(
                reinterpret_cast<const v4f*>(x + (size_t)rn * DIM + d0));

        // partial dot of this thread's 4 elements against each w1 row
        float p[8];
#pragma unroll
        for (int q = 0; q < NQ; ++q)
            p[q] = fmaf(xv.x, w1f[q][0],
                   fmaf(xv.y, w1f[q][1],
                   fmaf(xv.z, w1f[q][2], xv.w * w1f[q][3])));
        p[6] = 0.f; p[7] = 0.f;

        // ---- VALU butterfly (DPP) ----
        float r4[4];
#pragma unroll
        for (int i = 0; i < 4; ++i) {
            float send = s1 ? p[i] : p[i + 4];
            float keep = s1 ? p[i + 4] : p[i];
            r4[i] = keep + dpp_mov<0xB1>(send);
        }
        float r2[2];
#pragma unroll
        for (int i = 0; i < 2; ++i) {
            float send = s2 ? r4[i] : r4[i + 2];
            float keep = s2 ? r4[i + 2] : r4[i];
            r2[i] = keep + dpp_mov<0x4E>(send);
        }
        float r1;
        {
            float send = s3 ? r2[0] : r2[1];
            float keep = s3 ? r2[1] : r2[0];
            r1 = keep + dpp_mov<0x141>(send);
        }
        r1 += dpp_mov<0x128>(r1);       // xor8 via row_ror:8
        r1 += __shfl_xor(r1, 16, 64);   // DS swizzle
        r1 += __shfl_xor(r1, 32, 64);   // DS permute

        if (lane < 8) red[par][wave][vperm] = r1;
        __syncthreads();

        // combine 4 wave partials with b128 broadcast reads, then cos
        const v4f* rp = reinterpret_cast<const v4f*>(&red[par][0][0]);
        v4f slo = (rp[0] + rp[2]) + (rp[4] + rp[6]);  // q0..q3
        v4f shi = (rp[1] + rp[3]) + (rp[5] + rp[7]);  // q4..q5 (zw unused)
        float qv[NQ];
        qv[0] = slo.x; qv[1] = slo.y; qv[2] = slo.z; qv[3] = slo.w;
        qv[4] = shi.x; qv[5] = shi.y;
#pragma unroll
        for (int q = 0; q < NQ; ++q)
            qv[q] = __cosf(qv[q] + b1f[q]) * ctf[q];

        v4f o = b2v;
#pragma unroll
        for (int q = 0; q < NQ; ++q) {
            o.x = fmaf(qv[q], w2f[0][q], o.x);
            o.y = fmaf(qv[q], w2f[1][q], o.y);
            o.z = fmaf(qv[q], w2f[2][q], o.z);
            o.w = fmaf(qv[q], w2f[3][q], o.w);
        }
        o.x = fmaxf(o.x, 0.f); o.y = fmaxf(o.y, 0.f);
        o.z = fmaxf(o.z, 0.f); o.w = fmaxf(o.w, 0.f);

        // non-temporal store: no allocation, no dirty-L3 eviction traffic
        __builtin_nontemporal_store(
            o, reinterpret_cast<v4f*>(out + (size_t)r * DIM + d0));

        xv = xn;
        r = rn;
        par ^= 1;
    }
}

extern "C" void kernel_launch(void* const* d_in, const int* in_sizes, int n_in,
                              void* d_out, int out_size, void* d_ws, size_t ws_size,
                              hipStream_t stream) {
    const float* x     = (const float*)d_in[0];
    const float* w1    = (const float*)d_in[1];
    const float* b1    = (const float*)d_in[2];
    const float* theta = (const float*)d_in[3];
    const float* w2    = (const float*)d_in[4];
    const float* b2    = (const float*)d_in[5];
    float* out = (float*)d_out;

    const int n_rows = in_sizes[0] / DIM;  // B*S = 65536
    const int blocks = 1024;               // 4 blocks/CU resident at <=128 VGPR
    ffq_fused<<<blocks, 256, 0, stream>>>(x, w1, b1, theta, w2, b2, out, n_rows);
}